// Round 2
// baseline (338.867 us; speedup 1.0000x reference)
//
#include <hip/hip_runtime.h>
#include <hip/hip_bf16.h>

#define N_NODES 2048
#define N_EDGES 16384
#define BB 8
#define CC 64
#define TT 12
#define BT 96          // B*T
#define OUT_DIM 64
#define EPSV 1e-7f

// ---------------- CSR build ----------------
__global__ __launch_bounds__(256) void k_deg(const int* __restrict__ dst, int* deg) {
    int e = blockIdx.x * 256 + threadIdx.x;
    if (e < N_EDGES) atomicAdd(&deg[dst[e]], 1);
}

__global__ __launch_bounds__(1024) void k_scan(const int* __restrict__ deg, int* __restrict__ offs) {
    __shared__ int s[1024];
    int t = threadIdx.x;
    int d0 = deg[2 * t], d1 = deg[2 * t + 1];
    int p = d0 + d1;
    s[t] = p;
    __syncthreads();
    for (int off = 1; off < 1024; off <<= 1) {
        int v = (t >= off) ? s[t - off] : 0;
        __syncthreads();
        s[t] += v;
        __syncthreads();
    }
    int incl = s[t];
    int excl = incl - p;
    offs[2 * t] = excl;
    offs[2 * t + 1] = excl + d0;
    if (t == 1023) offs[2048] = incl;
}

__global__ __launch_bounds__(256) void k_fill(const int* __restrict__ dst, const int* __restrict__ src,
                                              const int* __restrict__ offs,
                                              int* cursor, int* __restrict__ csr_e, int* __restrict__ csr_s) {
    int e = blockIdx.x * 256 + threadIdx.x;
    if (e < N_EDGES) {
        int d = dst[e];
        int pos = atomicAdd(&cursor[d], 1);
        int slot = offs[d] + pos;
        csr_e[slot] = e;
        csr_s[slot] = src[e];
    }
}

// ---------------- transpose [B,C,T,N] -> h[N,BT,C] ----------------
__global__ __launch_bounds__(256) void k_transpose(const float* __restrict__ nf, float* __restrict__ h) {
    __shared__ float lds[64][65];
    int blk = blockIdx.x;
    int nt = blk & 31;       // 32 n-tiles
    int bt = blk >> 5;       // 96 (b,t)
    int b = bt / TT, t = bt - b * TT;
    int lane = threadIdx.x & 63;
    int row = threadIdx.x >> 6;   // 0..3
#pragma unroll
    for (int i = 0; i < 16; ++i) {
        int c = row * 16 + i;
        lds[c][lane] = nf[((b * CC + c) * TT + t) * N_NODES + nt * 64 + lane];
    }
    __syncthreads();
#pragma unroll
    for (int i = 0; i < 16; ++i) {
        int n = row * 16 + i;
        h[((nt * 64 + n) * BT + bt) * CC + lane] = lds[lane][n];
    }
}

// ---------------- fused aggregate + matmul + transposed store ----------------
// block = 256 threads = 4 waves; block handles 64 consecutive nodes for one (b,t).
// Phase 1: wave w aggregates nodes [w*16, w*16+16), lane = channel c.
// Phase 2: lane = n_rel (coalesced out writes), wave w covers o in [w*16, w*16+16).
__global__ __launch_bounds__(256) void k_agg(const float* __restrict__ h,
                                             const int* __restrict__ offs,
                                             const int* __restrict__ csr_e, const int* __restrict__ csr_s,
                                             const float* __restrict__ ef,
                                             const float* __restrict__ W, const float* __restrict__ bias,
                                             float* __restrict__ out) {
    __shared__ float Wl[64 * 64];
    __shared__ float fs[64][65];
    int tid = threadIdx.x;
    for (int i = tid; i < 64 * 64; i += 256) Wl[i] = W[i];

    int blk = blockIdx.x;
    int nt = blk & 31;       // n-tile; consecutive blocks share bt -> L2 locality
    int bt = blk >> 5;
    int b = bt / TT, t = bt - b * TT;
    int wave = tid >> 6, lane = tid & 63;

    for (int i = 0; i < 16; ++i) {
        int n = __builtin_amdgcn_readfirstlane(nt * 64 + wave * 16 + i);
        float hn = h[(n * BT + bt) * CC + lane];
        int k0 = __builtin_amdgcn_readfirstlane(offs[n]);
        int k1 = __builtin_amdgcn_readfirstlane(offs[n + 1]);
        float m_run = -1e30f, denom = 0.f, wsum = 0.f;
        int e_nx = 0, s_nx = 0;
        if (k0 < k1) {
            e_nx = __builtin_amdgcn_readfirstlane(csr_e[k0]);
            s_nx = __builtin_amdgcn_readfirstlane(csr_s[k0]);
        }
        for (int k = k0; k < k1; ++k) {
            int e = e_nx, s = s_nx;
            if (k + 1 < k1) {   // prefetch next edge's indices (overlaps msg math)
                e_nx = __builtin_amdgcn_readfirstlane(csr_e[k + 1]);
                s_nx = __builtin_amdgcn_readfirstlane(csr_s[k + 1]);
            }
            float hs = h[(s * BT + bt) * CC + lane];
            float ev = ef[e * CC + lane];
            float msg = fmaxf(hs + ev, 0.f) + EPSV;
            float nm = fmaxf(m_run, msg);
            float corr = __expf(m_run - nm);
            float p = __expf(msg - nm);
            denom = denom * corr + p;
            wsum = wsum * corr + p * msg;
            m_run = nm;
        }
        float agg = (k1 > k0) ? (wsum / denom) : 0.f;
        fs[wave * 16 + i][lane] = hn + agg;
    }
    __syncthreads();

    float acc[16];
#pragma unroll
    for (int j = 0; j < 16; ++j) acc[j] = bias[wave * 16 + j];
    for (int c = 0; c < 64; ++c) {
        float v = fs[lane][c];                 // stride 65 -> conflict-free
#pragma unroll
        for (int j = 0; j < 16; ++j)
            acc[j] += v * Wl[c * 64 + wave * 16 + j];   // wave-uniform -> LDS broadcast
    }
#pragma unroll
    for (int j = 0; j < 16; ++j) {
        int o = wave * 16 + j;
        out[((b * OUT_DIM + o) * TT + t) * N_NODES + nt * 64 + lane] = acc[j];
    }
}

extern "C" void kernel_launch(void* const* d_in, const int* in_sizes, int n_in,
                              void* d_out, int out_size, void* d_ws, size_t ws_size,
                              hipStream_t stream) {
    const float* nf  = (const float*)d_in[0];   // [B,C,T,N]
    const float* ef  = (const float*)d_in[1];   // [E,1,1,C]
    const int*   src = (const int*)d_in[2];
    const int*   dst = (const int*)d_in[3];
    const float* W   = (const float*)d_in[4];   // [C,OUT]
    const float* bia = (const float*)d_in[5];   // [OUT]
    float* out = (float*)d_out;

    float* h    = (float*)d_ws;                         // N*BT*C floats = 48 MiB
    int* deg    = (int*)(h + (size_t)N_NODES * BT * CC);
    int* offs   = deg + N_NODES;                        // N+1
    int* cursor = offs + (N_NODES + 1);
    int* csr_e  = cursor + N_NODES;                     // E
    int* csr_s  = csr_e + N_EDGES;                      // E

    hipMemsetAsync(deg, 0, sizeof(int) * (N_NODES + (N_NODES + 1) + N_NODES), stream);
    k_deg<<<N_EDGES / 256, 256, 0, stream>>>(dst, deg);
    k_scan<<<1, 1024, 0, stream>>>(deg, offs);
    k_fill<<<N_EDGES / 256, 256, 0, stream>>>(dst, src, offs, cursor, csr_e, csr_s);
    k_transpose<<<32 * BT, 256, 0, stream>>>(nf, h);
    k_agg<<<32 * BT, 256, 0, stream>>>(h, offs, csr_e, csr_s, ef, W, bia, out);
}